// Round 1
// baseline (1746.520 us; speedup 1.0000x reference)
//
#include <hip/hip_runtime.h>

#define EMB_D 64

// ---------------------------------------------------------------------------
// Kernel 1: degree count (deg stored as float, +1 smoothing applied later)
// ---------------------------------------------------------------------------
__global__ void degree_kernel(const int* __restrict__ eu, const int* __restrict__ ei,
                              int E, int U, float* __restrict__ deg) {
    int e = blockIdx.x * blockDim.x + threadIdx.x;
    if (e < E) {
        atomicAdd(&deg[eu[e]], 1.0f);
        atomicAdd(&deg[U + ei[e]], 1.0f);
    }
}

// ---------------------------------------------------------------------------
// Kernel 2: norm[m] = rsqrt(deg[m] + 1)  (in-place on deg buffer)
// ---------------------------------------------------------------------------
__global__ void norm_kernel(float* __restrict__ deg, int M) {
    int m = blockIdx.x * blockDim.x + threadIdx.x;
    if (m < M) deg[m] = rsqrtf(deg[m] + 1.0f);
}

// ---------------------------------------------------------------------------
// Kernel 3: cur = concat(user_emb, item_emb); out = 0.25 * cur
// ---------------------------------------------------------------------------
__global__ void init_kernel(const float* __restrict__ ue, const float* __restrict__ ie,
                            int U, long total, float* __restrict__ cur,
                            float* __restrict__ out) {
    long stride = (long)gridDim.x * blockDim.x;
    long ubound = (long)U * EMB_D;
    for (long idx = (long)blockIdx.x * blockDim.x + threadIdx.x; idx < total; idx += stride) {
        float v = (idx < ubound) ? ue[idx] : ie[idx - ubound];
        cur[idx] = v;
        out[idx] = 0.25f * v;
    }
}

// ---------------------------------------------------------------------------
// Kernel 4: bipartite propagation — one wave (64 lanes) per undirected edge.
// lane d owns embedding dim d. Both directions with the same weight.
// ---------------------------------------------------------------------------
__global__ void __launch_bounds__(256) prop_edges(const int* __restrict__ eu,
                                                  const int* __restrict__ ei,
                                                  int E, int U,
                                                  const float* __restrict__ norm,
                                                  const float* __restrict__ cur,
                                                  float* __restrict__ nxt) {
    int wid  = (int)((blockIdx.x * (long)blockDim.x + threadIdx.x) >> 6);
    int lane = threadIdx.x & 63;
    if (wid >= E) return;
    int u = eu[wid];
    int i = U + ei[wid];
    float w  = norm[u] * norm[i];          // same-address broadcast loads
    long ou  = (long)u * EMB_D + lane;
    long oi  = (long)i * EMB_D + lane;
    float cu = cur[ou];
    float ci = cur[oi];
    atomicAdd(&nxt[ou], w * ci);
    atomicAdd(&nxt[oi], w * cu);
}

// ---------------------------------------------------------------------------
// Kernel 5: s_hat item-item propagation — one wave per s-edge, one direction.
// ---------------------------------------------------------------------------
__global__ void __launch_bounds__(256) prop_sedges(const int* __restrict__ sr,
                                                   const int* __restrict__ sc,
                                                   const float* __restrict__ sv,
                                                   int S, int U,
                                                   const float* __restrict__ cur,
                                                   float* __restrict__ nxt) {
    int wid  = (int)((blockIdx.x * (long)blockDim.x + threadIdx.x) >> 6);
    int lane = threadIdx.x & 63;
    if (wid >= S) return;
    int r = U + sr[wid];
    int c = U + sc[wid];
    float v = sv[wid];
    atomicAdd(&nxt[(long)r * EMB_D + lane], v * cur[(long)c * EMB_D + lane]);
}

// ---------------------------------------------------------------------------
// Kernel 6: out += 0.25 * nxt
// ---------------------------------------------------------------------------
__global__ void accum_kernel(const float* __restrict__ nxt, float* __restrict__ out,
                             long total) {
    long stride = (long)gridDim.x * blockDim.x;
    for (long idx = (long)blockIdx.x * blockDim.x + threadIdx.x; idx < total; idx += stride) {
        out[idx] += 0.25f * nxt[idx];
    }
}

extern "C" void kernel_launch(void* const* d_in, const int* in_sizes, int n_in,
                              void* d_out, int out_size, void* d_ws, size_t ws_size,
                              hipStream_t stream) {
    const float* user_emb = (const float*)d_in[0];
    const float* item_emb = (const float*)d_in[1];
    const int*   edge_user = (const int*)d_in[2];
    const int*   edge_item = (const int*)d_in[3];
    const int*   s_row = (const int*)d_in[4];
    const int*   s_col = (const int*)d_in[5];
    const float* s_val = (const float*)d_in[6];
    float* out = (float*)d_out;

    const int U = in_sizes[0] / EMB_D;
    const int I = in_sizes[1] / EMB_D;
    const int M = U + I;
    const int E = in_sizes[2];
    const int S = in_sizes[4];
    const long MD = (long)M * EMB_D;

    // workspace layout: bufA [MD] | bufB [MD] | norm [M]
    float* bufA = (float*)d_ws;
    float* bufB = bufA + MD;
    float* norm = bufB + MD;

    // 1) degrees -> norm
    hipMemsetAsync(norm, 0, M * sizeof(float), stream);
    degree_kernel<<<(E + 255) / 256, 256, 0, stream>>>(edge_user, edge_item, E, U, norm);
    norm_kernel<<<(M + 255) / 256, 256, 0, stream>>>(norm, M);

    // 2) init cur and out
    init_kernel<<<2048, 256, 0, stream>>>(user_emb, item_emb, U, MD, bufA, out);

    // 3) L=3 propagation layers
    float* cur = bufA;
    float* nxt = bufB;
    for (int l = 0; l < 3; ++l) {
        hipMemsetAsync(nxt, 0, MD * sizeof(float), stream);
        prop_edges<<<(int)(((long)E * 64 + 255) / 256), 256, 0, stream>>>(
            edge_user, edge_item, E, U, norm, cur, nxt);
        prop_sedges<<<(int)(((long)S * 64 + 255) / 256), 256, 0, stream>>>(
            s_row, s_col, s_val, S, U, cur, nxt);
        accum_kernel<<<2048, 256, 0, stream>>>(nxt, out, MD);
        float* t = cur; cur = nxt; nxt = t;
    }
}

// Round 2
// 1002.916 us; speedup vs baseline: 1.7414x; 1.7414x over previous
//
#include <hip/hip_runtime.h>

#define EMB_D 64

// ---------------------------------------------------------------------------
// degree of bipartite graph (both directions), int counts
// ---------------------------------------------------------------------------
__global__ void deg_bip_kernel(const int* __restrict__ eu, const int* __restrict__ ei,
                               int E, int U, int* __restrict__ deg) {
    int e = blockIdx.x * blockDim.x + threadIdx.x;
    if (e < E) {
        atomicAdd(&deg[eu[e]], 1);
        atomicAdd(&deg[U + ei[e]], 1);
    }
}

// norm[m] = rsqrt(deg[m] + 1)   (reads int deg, writes separate norm array)
__global__ void norm_kernel(const int* __restrict__ deg, float* __restrict__ norm, int M) {
    int m = blockIdx.x * blockDim.x + threadIdx.x;
    if (m < M) norm[m] = rsqrtf((float)deg[m] + 1.0f);
}

// add s-edge row counts on top of bipartite degrees -> total CSR row lengths
__global__ void deg_s_kernel(const int* __restrict__ sr, int S, int U, int* __restrict__ deg) {
    int e = blockIdx.x * blockDim.x + threadIdx.x;
    if (e < S) atomicAdd(&deg[U + sr[e]], 1);
}

// ---------------------------------------------------------------------------
// 3-kernel exclusive scan of deg[M] -> rowptr[M+1], cursor[M]
// ---------------------------------------------------------------------------
__global__ void __launch_bounds__(1024) scan_block(const int* __restrict__ deg,
                                                   int* __restrict__ incl,
                                                   int* __restrict__ bsum, int M) {
    __shared__ int sh[1024];
    int i = blockIdx.x * 1024 + threadIdx.x;
    int v = (i < M) ? deg[i] : 0;
    sh[threadIdx.x] = v;
    __syncthreads();
    for (int ofs = 1; ofs < 1024; ofs <<= 1) {
        int t = (threadIdx.x >= ofs) ? sh[threadIdx.x - ofs] : 0;
        __syncthreads();
        sh[threadIdx.x] += t;
        __syncthreads();
    }
    if (i < M) incl[i] = sh[threadIdx.x];
    if (threadIdx.x == 1023) bsum[blockIdx.x] = sh[1023];
}

__global__ void __launch_bounds__(256) scan_bsum(int* __restrict__ bsum, int nb) {
    __shared__ int sh[256];
    int v = (threadIdx.x < nb) ? bsum[threadIdx.x] : 0;
    sh[threadIdx.x] = v;
    __syncthreads();
    for (int ofs = 1; ofs < 256; ofs <<= 1) {
        int t = (threadIdx.x >= ofs) ? sh[threadIdx.x - ofs] : 0;
        __syncthreads();
        sh[threadIdx.x] += t;
        __syncthreads();
    }
    // exclusive block offset = inclusive - own
    if (threadIdx.x < nb) bsum[threadIdx.x] = sh[threadIdx.x] - v;
}

__global__ void finalize_rowptr(const int* __restrict__ incl, const int* __restrict__ deg,
                                const int* __restrict__ bsum, int* __restrict__ rowptr,
                                int* __restrict__ cursor, int M) {
    int i = blockIdx.x * blockDim.x + threadIdx.x;
    if (i < M) {
        int v = incl[i] - deg[i] + bsum[i >> 10];   // exclusive prefix
        rowptr[i] = v;
        cursor[i] = v;
    } else if (i == M) {
        rowptr[M] = incl[M - 1] + bsum[(M - 1) >> 10];  // total
    }
}

// ---------------------------------------------------------------------------
// scatter edges into CSR slots (order within a row is racy -> rounding jitter only)
// ---------------------------------------------------------------------------
__global__ void scatter_bip(const int* __restrict__ eu, const int* __restrict__ ei,
                            int E, int U, const float* __restrict__ norm,
                            int* __restrict__ cursor, int* __restrict__ col,
                            float* __restrict__ w) {
    int e = blockIdx.x * blockDim.x + threadIdx.x;
    if (e >= E) return;
    int u = eu[e];
    int iv = U + ei[e];
    float ww = norm[u] * norm[iv];
    int p1 = atomicAdd(&cursor[u], 1);
    col[p1] = iv; w[p1] = ww;
    int p2 = atomicAdd(&cursor[iv], 1);
    col[p2] = u; w[p2] = ww;
}

__global__ void scatter_s(const int* __restrict__ sr, const int* __restrict__ sc,
                          const float* __restrict__ sv, int S, int U,
                          int* __restrict__ cursor, int* __restrict__ col,
                          float* __restrict__ w) {
    int e = blockIdx.x * blockDim.x + threadIdx.x;
    if (e >= S) return;
    int r = U + sr[e];
    int p = atomicAdd(&cursor[r], 1);
    col[p] = U + sc[e];
    w[p] = sv[e];
}

// ---------------------------------------------------------------------------
// cur = concat(user_emb, item_emb); out = 0.25 * cur
// ---------------------------------------------------------------------------
__global__ void init_kernel(const float* __restrict__ ue, const float* __restrict__ ie,
                            int U, long total, float* __restrict__ cur,
                            float* __restrict__ out) {
    long stride = (long)gridDim.x * blockDim.x;
    long ubound = (long)U * EMB_D;
    for (long idx = (long)blockIdx.x * blockDim.x + threadIdx.x; idx < total; idx += stride) {
        float v = (idx < ubound) ? ue[idx] : ie[idx - ubound];
        cur[idx] = v;
        out[idx] = 0.25f * v;
    }
}

// ---------------------------------------------------------------------------
// gather: one wave per destination node, lane = embedding dim.
// nxt[m] = sum_j w[j]*cur[col[j]]; out[m] += 0.25*nxt[m]  (fused)
// ---------------------------------------------------------------------------
__global__ void __launch_bounds__(256) gather_kernel(const int* __restrict__ rowptr,
                                                     const int* __restrict__ col,
                                                     const float* __restrict__ w,
                                                     const float* __restrict__ cur,
                                                     float* __restrict__ nxt,
                                                     float* __restrict__ out, int M) {
    int wid  = (int)((blockIdx.x * (long)blockDim.x + threadIdx.x) >> 6);
    int lane = threadIdx.x & 63;
    if (wid >= M) return;
    int beg = rowptr[wid];
    int end = rowptr[wid + 1];
    float acc = 0.0f;
    int j = beg;
    if (j < end) {
        // 2-deep software pipeline: col/w load for j+1 overlaps cur load for j
        int cc = col[j];
        float ww = w[j];
        for (; j + 1 < end; ++j) {
            int cn = col[j + 1];
            float wn = w[j + 1];
            acc += ww * cur[cc * EMB_D + lane];
            cc = cn; ww = wn;
        }
        acc += ww * cur[cc * EMB_D + lane];
    }
    int o = wid * EMB_D + lane;
    nxt[o] = acc;
    out[o] += 0.25f * acc;
}

extern "C" void kernel_launch(void* const* d_in, const int* in_sizes, int n_in,
                              void* d_out, int out_size, void* d_ws, size_t ws_size,
                              hipStream_t stream) {
    const float* user_emb = (const float*)d_in[0];
    const float* item_emb = (const float*)d_in[1];
    const int*   edge_user = (const int*)d_in[2];
    const int*   edge_item = (const int*)d_in[3];
    const int*   s_row = (const int*)d_in[4];
    const int*   s_col = (const int*)d_in[5];
    const float* s_val = (const float*)d_in[6];
    float* out = (float*)d_out;

    const int U = in_sizes[0] / EMB_D;
    const int I = in_sizes[1] / EMB_D;
    const int M = U + I;
    const int E = in_sizes[2];
    const int S = in_sizes[4];
    const long MD = (long)M * EMB_D;
    const long NT = 2L * E + S;           // total CSR entries

    // workspace carve-up (all 4-byte elements)
    char* p = (char*)d_ws;
    float* bufA   = (float*)p;            p += MD * sizeof(float);
    float* bufB   = (float*)p;            p += MD * sizeof(float);
    float* norm   = (float*)p;            p += (long)M * sizeof(float);
    int*   deg    = (int*)p;              p += (long)M * sizeof(int);
    int*   incl   = (int*)p;              p += (long)M * sizeof(int);
    int*   rowptr = (int*)p;              p += (long)(M + 1) * sizeof(int);
    int*   cursor = (int*)p;              p += (long)M * sizeof(int);
    int*   bsum   = (int*)p;              p += 256 * sizeof(int);
    int*   colA   = (int*)p;              p += NT * sizeof(int);
    float* wA     = (float*)p;            p += NT * sizeof(float);

    const int nb = (M + 1023) / 1024;     // scan blocks (147 for M=150000)

    // 1) degrees -> norm -> total CSR degrees
    hipMemsetAsync(deg, 0, M * sizeof(int), stream);
    deg_bip_kernel<<<(E + 255) / 256, 256, 0, stream>>>(edge_user, edge_item, E, U, deg);
    norm_kernel<<<(M + 255) / 256, 256, 0, stream>>>(deg, norm, M);
    deg_s_kernel<<<(S + 255) / 256, 256, 0, stream>>>(s_row, S, U, deg);

    // 2) exclusive scan -> rowptr, cursor
    scan_block<<<nb, 1024, 0, stream>>>(deg, incl, bsum, M);
    scan_bsum<<<1, 256, 0, stream>>>(bsum, nb);
    finalize_rowptr<<<(M + 256) / 256, 256, 0, stream>>>(incl, deg, bsum, rowptr, cursor, M);

    // 3) scatter edges into CSR
    scatter_bip<<<(E + 255) / 256, 256, 0, stream>>>(edge_user, edge_item, E, U, norm,
                                                     cursor, colA, wA);
    scatter_s<<<(S + 255) / 256, 256, 0, stream>>>(s_row, s_col, s_val, S, U,
                                                   cursor, colA, wA);

    // 4) init cur and out
    init_kernel<<<2048, 256, 0, stream>>>(user_emb, item_emb, U, MD, bufA, out);

    // 5) L=3 gather layers (fused accumulate into out)
    float* cur = bufA;
    float* nxt = bufB;
    const int gblocks = (int)(((long)M * 64 + 255) / 256);
    for (int l = 0; l < 3; ++l) {
        gather_kernel<<<gblocks, 256, 0, stream>>>(rowptr, colA, wA, cur, nxt, out, M);
        float* t = cur; cur = nxt; nxt = t;
    }
}

// Round 3
// 572.674 us; speedup vs baseline: 3.0498x; 1.7513x over previous
//
#include <hip/hip_runtime.h>

#define EMB_D 64

typedef float float4v __attribute__((ext_vector_type(4)));

// ---------------------------------------------------------------------------
// degree of bipartite graph (both directions), int counts
// ---------------------------------------------------------------------------
__global__ void deg_bip_kernel(const int* __restrict__ eu, const int* __restrict__ ei,
                               int E, int U, int* __restrict__ deg) {
    int e = blockIdx.x * blockDim.x + threadIdx.x;
    if (e < E) {
        atomicAdd(&deg[eu[e]], 1);
        atomicAdd(&deg[U + ei[e]], 1);
    }
}

// norm[m] = rsqrt(deg[m] + 1)
__global__ void norm_kernel(const int* __restrict__ deg, float* __restrict__ norm, int M) {
    int m = blockIdx.x * blockDim.x + threadIdx.x;
    if (m < M) norm[m] = rsqrtf((float)deg[m] + 1.0f);
}

// add s-edge row counts -> total CSR row lengths
__global__ void deg_s_kernel(const int* __restrict__ sr, int S, int U, int* __restrict__ deg) {
    int e = blockIdx.x * blockDim.x + threadIdx.x;
    if (e < S) atomicAdd(&deg[U + sr[e]], 1);
}

// ---------------------------------------------------------------------------
// 3-kernel exclusive scan of deg[M] -> rowptr[M+1], cursor[M]
// ---------------------------------------------------------------------------
__global__ void __launch_bounds__(1024) scan_block(const int* __restrict__ deg,
                                                   int* __restrict__ incl,
                                                   int* __restrict__ bsum, int M) {
    __shared__ int sh[1024];
    int i = blockIdx.x * 1024 + threadIdx.x;
    int v = (i < M) ? deg[i] : 0;
    sh[threadIdx.x] = v;
    __syncthreads();
    for (int ofs = 1; ofs < 1024; ofs <<= 1) {
        int t = (threadIdx.x >= ofs) ? sh[threadIdx.x - ofs] : 0;
        __syncthreads();
        sh[threadIdx.x] += t;
        __syncthreads();
    }
    if (i < M) incl[i] = sh[threadIdx.x];
    if (threadIdx.x == 1023) bsum[blockIdx.x] = sh[1023];
}

__global__ void __launch_bounds__(256) scan_bsum(int* __restrict__ bsum, int nb) {
    __shared__ int sh[256];
    int v = (threadIdx.x < nb) ? bsum[threadIdx.x] : 0;
    sh[threadIdx.x] = v;
    __syncthreads();
    for (int ofs = 1; ofs < 256; ofs <<= 1) {
        int t = (threadIdx.x >= ofs) ? sh[threadIdx.x - ofs] : 0;
        __syncthreads();
        sh[threadIdx.x] += t;
        __syncthreads();
    }
    if (threadIdx.x < nb) bsum[threadIdx.x] = sh[threadIdx.x] - v;  // exclusive
}

__global__ void finalize_rowptr(const int* __restrict__ incl, const int* __restrict__ deg,
                                const int* __restrict__ bsum, int* __restrict__ rowptr,
                                int* __restrict__ cursor, int M) {
    int i = blockIdx.x * blockDim.x + threadIdx.x;
    if (i < M) {
        int v = incl[i] - deg[i] + bsum[i >> 10];
        rowptr[i] = v;
        cursor[i] = v;
    } else if (i == M) {
        rowptr[M] = incl[M - 1] + bsum[(M - 1) >> 10];
    }
}

// ---------------------------------------------------------------------------
// scatter edges into packed (col, w_bits) CSR entries
// ---------------------------------------------------------------------------
__global__ void scatter_bip(const int* __restrict__ eu, const int* __restrict__ ei,
                            int E, int U, const float* __restrict__ norm,
                            int* __restrict__ cursor, int2* __restrict__ ent) {
    int e = blockIdx.x * blockDim.x + threadIdx.x;
    if (e >= E) return;
    int u = eu[e];
    int iv = U + ei[e];
    float ww = norm[u] * norm[iv];
    int wb = __float_as_int(ww);
    int p1 = atomicAdd(&cursor[u], 1);
    ent[p1] = make_int2(iv, wb);
    int p2 = atomicAdd(&cursor[iv], 1);
    ent[p2] = make_int2(u, wb);
}

__global__ void scatter_s(const int* __restrict__ sr, const int* __restrict__ sc,
                          const float* __restrict__ sv, int S, int U,
                          int* __restrict__ cursor, int2* __restrict__ ent) {
    int e = blockIdx.x * blockDim.x + threadIdx.x;
    if (e >= S) return;
    int r = U + sr[e];
    int p = atomicAdd(&cursor[r], 1);
    ent[p] = make_int2(U + sc[e], __float_as_int(sv[e]));
}

// ---------------------------------------------------------------------------
// cur = concat(user_emb, item_emb); out = 0.25 * cur   (float4)
// ---------------------------------------------------------------------------
__global__ void init_kernel(const float4v* __restrict__ ue, const float4v* __restrict__ ie,
                            long u4, long total4, float4v* __restrict__ cur,
                            float4v* __restrict__ out) {
    long stride = (long)gridDim.x * blockDim.x;
    for (long idx = (long)blockIdx.x * blockDim.x + threadIdx.x; idx < total4; idx += stride) {
        float4v v = (idx < u4) ? ue[idx] : ie[idx - u4];
        cur[idx] = v;
        out[idx] = 0.25f * v;
    }
}

// ---------------------------------------------------------------------------
// gather: one wave per destination node; 4 edge-groups x 16 lanes x float4.
// Each group processes one edge per iteration (16 lanes cover the 256B row).
// 2-deep pipeline on row loads -> 8 outstanding row loads per wave.
// ---------------------------------------------------------------------------
template <bool STORE_NXT>
__global__ void __launch_bounds__(256) gather_kernel(const int* __restrict__ rowptr,
                                                     const int2* __restrict__ ent,
                                                     const float* __restrict__ cur,
                                                     float* __restrict__ nxt,
                                                     float* __restrict__ out, int M) {
    int wid  = (int)((blockIdx.x * (long)blockDim.x + threadIdx.x) >> 6);
    int lane = threadIdx.x & 63;
    int g    = lane >> 4;       // edge group 0..3
    int l    = lane & 15;       // float4 slot within row
    if (wid >= M) return;
    int beg = rowptr[wid];
    int end = rowptr[wid + 1];

    float4v acc = {0.f, 0.f, 0.f, 0.f};
    int j = beg + g;
    if (j < end) {
        int2 e0 = ent[j];
        const float4v* r0 = (const float4v*)(cur + (long)e0.x * EMB_D);
        float4v v0 = r0[l];
        float  w0 = __int_as_float(e0.y);
        j += 4;
        for (; j < end; j += 4) {
            int2 e1 = ent[j];
            const float4v* r1 = (const float4v*)(cur + (long)e1.x * EMB_D);
            float4v v1 = r1[l];                 // issue before consuming v0
            float  w1 = __int_as_float(e1.y);
            acc += w0 * v0;
            v0 = v1; w0 = w1;
        }
        acc += w0 * v0;
    }
    // reduce across the 4 groups (lanes l, l+16, l+32, l+48)
    acc.x += __shfl_xor(acc.x, 16); acc.y += __shfl_xor(acc.y, 16);
    acc.z += __shfl_xor(acc.z, 16); acc.w += __shfl_xor(acc.w, 16);
    acc.x += __shfl_xor(acc.x, 32); acc.y += __shfl_xor(acc.y, 32);
    acc.z += __shfl_xor(acc.z, 32); acc.w += __shfl_xor(acc.w, 32);

    if (g == 0) {
        long o4 = (long)wid * 16 + l;
        if (STORE_NXT) ((float4v*)nxt)[o4] = acc;
        float4v* o = (float4v*)out;
        o[o4] += 0.25f * acc;
    }
}

extern "C" void kernel_launch(void* const* d_in, const int* in_sizes, int n_in,
                              void* d_out, int out_size, void* d_ws, size_t ws_size,
                              hipStream_t stream) {
    const float* user_emb = (const float*)d_in[0];
    const float* item_emb = (const float*)d_in[1];
    const int*   edge_user = (const int*)d_in[2];
    const int*   edge_item = (const int*)d_in[3];
    const int*   s_row = (const int*)d_in[4];
    const int*   s_col = (const int*)d_in[5];
    const float* s_val = (const float*)d_in[6];
    float* out = (float*)d_out;

    const int U = in_sizes[0] / EMB_D;
    const int I = in_sizes[1] / EMB_D;
    const int M = U + I;
    const int E = in_sizes[2];
    const int S = in_sizes[4];
    const long MD = (long)M * EMB_D;
    const long NT = 2L * E + S;

    // workspace carve-up, 16B-aligned chunks
    char* p = (char*)d_ws;
    auto carve = [&](long bytes) {
        char* q = p;
        p += (bytes + 15) & ~15L;
        return q;
    };
    float* bufA   = (float*)carve(MD * sizeof(float));
    float* bufB   = (float*)carve(MD * sizeof(float));
    float* norm   = (float*)carve((long)M * sizeof(float));
    int*   deg    = (int*)carve((long)M * sizeof(int));
    int*   incl   = (int*)carve((long)M * sizeof(int));
    int*   rowptr = (int*)carve((long)(M + 1) * sizeof(int));
    int*   cursor = (int*)carve((long)M * sizeof(int));
    int*   bsum   = (int*)carve(256 * sizeof(int));
    int2*  ent    = (int2*)carve(NT * sizeof(int2));

    const int nb = (M + 1023) / 1024;

    // 1) degrees -> norm -> total CSR degrees
    hipMemsetAsync(deg, 0, M * sizeof(int), stream);
    deg_bip_kernel<<<(E + 255) / 256, 256, 0, stream>>>(edge_user, edge_item, E, U, deg);
    norm_kernel<<<(M + 255) / 256, 256, 0, stream>>>(deg, norm, M);
    deg_s_kernel<<<(S + 255) / 256, 256, 0, stream>>>(s_row, S, U, deg);

    // 2) exclusive scan -> rowptr, cursor
    scan_block<<<nb, 1024, 0, stream>>>(deg, incl, bsum, M);
    scan_bsum<<<1, 256, 0, stream>>>(bsum, nb);
    finalize_rowptr<<<(M + 256) / 256, 256, 0, stream>>>(incl, deg, bsum, rowptr, cursor, M);

    // 3) scatter edges into packed CSR
    scatter_bip<<<(E + 255) / 256, 256, 0, stream>>>(edge_user, edge_item, E, U, norm,
                                                     cursor, ent);
    scatter_s<<<(S + 255) / 256, 256, 0, stream>>>(s_row, s_col, s_val, S, U, cursor, ent);

    // 4) init cur and out (float4)
    init_kernel<<<2048, 256, 0, stream>>>((const float4v*)user_emb, (const float4v*)item_emb,
                                          (long)U * (EMB_D / 4), MD / 4,
                                          (float4v*)bufA, (float4v*)out);

    // 5) L=3 gather layers (fused accumulate into out; last layer skips nxt store)
    float* cur = bufA;
    float* nxt = bufB;
    const int gblocks = (int)(((long)M * 64 + 255) / 256);
    gather_kernel<true><<<gblocks, 256, 0, stream>>>(rowptr, ent, cur, nxt, out, M);
    gather_kernel<true><<<gblocks, 256, 0, stream>>>(rowptr, ent, nxt, cur, out, M);
    gather_kernel<false><<<gblocks, 256, 0, stream>>>(rowptr, ent, cur, nullptr, out, M);
}